// Round 1
// baseline (1649.545 us; speedup 1.0000x reference)
//
#include <hip/hip_runtime.h>

#define N_NODES 100000
#define N_EDGES 1250000

// ---------------------------------------------------------------------------
// Node projection: vsk = feat@W_vsk + b_vsk ; vrk = feat@W_vrk + b_vrk
// 1-wave (64-thread) blocks, lane = output column c.
// W columns live in VGPRs; feat row elements are wave-uniform -> scalar loads.
// ---------------------------------------------------------------------------
__global__ __launch_bounds__(64) void node_kernel(
    const float* __restrict__ feat,
    const float* __restrict__ Wv, const float* __restrict__ bv,
    const float* __restrict__ Wr, const float* __restrict__ br,
    float* __restrict__ vsk, float* __restrict__ vrk)
{
    const int lane = threadIdx.x;
    float wv[64], wr[64];
#pragma unroll
    for (int k = 0; k < 64; ++k) {
        wv[k] = Wv[k * 64 + lane];   // coalesced
        wr[k] = Wr[k * 64 + lane];
    }
    const float bvv = bv[lane];
    const float brv = br[lane];

    const int r0 = blockIdx.x * 64;
    const int rmax = (N_NODES - r0 < 64) ? (N_NODES - r0) : 64;

    for (int j = 0; j < rmax; ++j) {
        const int r = r0 + j;
        // 4 independent partial sums per output to break fmac dep chains
        float a0 = 0.f, a1 = 0.f, a2 = 0.f, a3 = 0.f;
        float b0 = 0.f, b1_ = 0.f, b2_ = 0.f, b3 = 0.f;
#pragma unroll
        for (int k4 = 0; k4 < 16; ++k4) {
            const int k = k4 * 4;
            const float x0 = feat[r * 64 + k + 0];  // uniform -> s_load
            const float x1 = feat[r * 64 + k + 1];
            const float x2 = feat[r * 64 + k + 2];
            const float x3 = feat[r * 64 + k + 3];
            a0 += x0 * wv[k + 0]; b0  += x0 * wr[k + 0];
            a1 += x1 * wv[k + 1]; b1_ += x1 * wr[k + 1];
            a2 += x2 * wv[k + 2]; b2_ += x2 * wr[k + 2];
            a3 += x3 * wv[k + 3]; b3  += x3 * wr[k + 3];
        }
        vsk[r * 64 + lane] = (a0 + a1) + (a2 + a3) + bvv;
        vrk[r * 64 + lane] = (b0 + b1_) + (b2_ + b3) + brv;
    }
}

// ---------------------------------------------------------------------------
// Fused edge kernel: h = relu(vsk[src] + vrk[dst] + efeat@Wek + bek)
//                    h1 = relu(h@W1 + b1); out = relu(h1@W2 + b2)
// 1-wave blocks, 64 edges per block. 16 KB xor-swizzled LDS scratch.
// Phase A lane=feature (coalesced gathers); phases B/C lane=edge with
// wave-uniform SGPR weight operands; phase D LDS transpose -> float4 stores.
// ---------------------------------------------------------------------------
__global__ __launch_bounds__(64) void edge_kernel(
    const float* __restrict__ efeat,
    const int*   __restrict__ src, const int* __restrict__ dst,
    const float* __restrict__ vsk, const float* __restrict__ vrk,
    const float* __restrict__ Wek, const float* __restrict__ bek,
    const float* __restrict__ W1,  const float* __restrict__ b1,
    const float* __restrict__ W2,  const float* __restrict__ b2,
    float* __restrict__ out)
{
    __shared__ float sH[64 * 64];   // 16 KB, xor-swizzled rows
    const int lane = threadIdx.x;
    const int e0 = blockIdx.x * 64;
    const int jmax = (N_EDGES - e0 < 64) ? (N_EDGES - e0) : 64;

    // Wek column for this lane in VGPRs + per-lane bias
    float wek[64];
#pragma unroll
    for (int k = 0; k < 64; ++k) wek[k] = Wek[k * 64 + lane];
    const float bekv = bek[lane];

    // ---- Phase A: per edge j (lane = feature column) ----
    for (int j = 0; j < jmax; ++j) {
        const int e = e0 + j;
        const int rs = src[e];            // uniform
        const int rd = dst[e];            // uniform
        const float gs = vsk[rs * 64 + lane];   // coalesced 256B gather
        const float gd = vrk[rd * 64 + lane];
        float a0 = 0.f, a1 = 0.f, a2 = 0.f, a3 = 0.f;
#pragma unroll
        for (int k4 = 0; k4 < 16; ++k4) {
            const int k = k4 * 4;
            const float x0 = efeat[e * 64 + k + 0];  // uniform -> s_load
            const float x1 = efeat[e * 64 + k + 1];
            const float x2 = efeat[e * 64 + k + 2];
            const float x3 = efeat[e * 64 + k + 3];
            a0 += x0 * wek[k + 0];
            a1 += x1 * wek[k + 1];
            a2 += x2 * wek[k + 2];
            a3 += x3 * wek[k + 3];
        }
        const float h = gs + gd + ((a0 + a1) + (a2 + a3)) + bekv;
        // swizzled write: row j, col lane; banks = lane^ (j&31): conflict-free
        sH[j * 64 + (lane ^ (j & 31))] = fmaxf(h, 0.f);
    }

    // ---- Phase B: layer 1, lane = edge ----
    float h1[64];
#pragma unroll
    for (int c = 0; c < 64; ++c) h1[c] = b1[c];   // uniform -> SGPR
    for (int k = 0; k < 64; ++k) {
        const float xk = sH[lane * 64 + (k ^ (lane & 31))];
#pragma unroll
        for (int c = 0; c < 64; ++c) h1[c] += xk * W1[k * 64 + c];  // W1 uniform
    }
    // write relu(h1) back to own swizzled row (all phase-B reads precede; same wave)
#pragma unroll
    for (int c = 0; c < 64; ++c)
        sH[lane * 64 + (c ^ (lane & 31))] = fmaxf(h1[c], 0.f);

    // ---- Phase C: layer 2, lane = edge ----
    float o[32];
#pragma unroll
    for (int c = 0; c < 32; ++c) o[c] = b2[c];    // uniform -> SGPR
    for (int k = 0; k < 64; ++k) {
        const float xk = sH[lane * 64 + (k ^ (lane & 31))];
#pragma unroll
        for (int c = 0; c < 32; ++c) o[c] += xk * W2[k * 32 + c];   // W2 uniform
    }

    // compiler barrier: keep phase-C LDS reads before phase-D overwrites
    __asm volatile("" ::: "memory");

    // ---- Phase D: transpose through LDS, coalesced float4 stores ----
    // out layout scratch: edge-major rows of 32, xor-swizzled
#pragma unroll
    for (int c = 0; c < 32; ++c)
        sH[lane * 32 + (c ^ (lane & 31))] = fmaxf(o[c], 0.f);

    __asm volatile("" ::: "memory");

#pragma unroll
    for (int i = 0; i < 8; ++i) {
        const int f = i * 256 + lane * 4;       // starting flat float index
        const int e = f >> 5;                   // local edge 0..63
        if (e < jmax) {
            const int c = f & 31;               // 4*(lane&7)
            const int base = e * 32;
            const int sw = e & 31;
            float4 v;
            v.x = sH[base + ((c + 0) ^ sw)];
            v.y = sH[base + ((c + 1) ^ sw)];
            v.z = sH[base + ((c + 2) ^ sw)];
            v.w = sH[base + ((c + 3) ^ sw)];
            *reinterpret_cast<float4*>(&out[(size_t)e0 * 32 + f]) = v;
        }
    }
}

extern "C" void kernel_launch(void* const* d_in, const int* in_sizes, int n_in,
                              void* d_out, int out_size, void* d_ws, size_t ws_size,
                              hipStream_t stream) {
    const float* feat  = (const float*)d_in[0];
    const float* efeat = (const float*)d_in[1];
    const int*   src   = (const int*)d_in[2];
    const int*   dst   = (const int*)d_in[3];
    const float* W_vsk = (const float*)d_in[4];
    const float* b_vsk = (const float*)d_in[5];
    const float* W_vrk = (const float*)d_in[6];
    const float* b_vrk = (const float*)d_in[7];
    const float* W_ek  = (const float*)d_in[8];
    const float* b_ek  = (const float*)d_in[9];
    const float* W1    = (const float*)d_in[10];
    const float* b1    = (const float*)d_in[11];
    const float* W2    = (const float*)d_in[12];
    const float* b2    = (const float*)d_in[13];
    float* out = (float*)d_out;

    // workspace: vsk (100000*64 f32 = 25.6 MB) + vrk (25.6 MB)
    float* vsk = (float*)d_ws;
    float* vrk = vsk + (size_t)N_NODES * 64;

    const int node_blocks = (N_NODES + 63) / 64;   // 1563
    const int edge_blocks = (N_EDGES + 63) / 64;   // 19532

    node_kernel<<<node_blocks, 64, 0, stream>>>(feat, W_vsk, b_vsk, W_vrk, b_vrk,
                                                vsk, vrk);
    edge_kernel<<<edge_blocks, 64, 0, stream>>>(efeat, src, dst, vsk, vrk,
                                                W_ek, b_ek, W1, b1, W2, b2, out);
}

// Round 2
// 677.094 us; speedup vs baseline: 2.4362x; 2.4362x over previous
//
#include <hip/hip_runtime.h>

#define N_NODES 100000
#define N_EDGES 1250000

typedef __bf16 bf16x8 __attribute__((ext_vector_type(8)));
typedef __bf16 bf16x4 __attribute__((ext_vector_type(4)));
typedef float  f32x4  __attribute__((ext_vector_type(4)));

#define MFMA16(a, b, c) __builtin_amdgcn_mfma_f32_16x16x32_bf16((a), (b), (c), 0, 0, 0)

// LDS address swizzle: 16B chunks xor'd by row&7 so A-frag b128 reads and
// row-major staging writes both hit the structural LDS minimum (no conflicts).
__device__ __forceinline__ int swz(int row, int k) {
    return row * 64 + (((k >> 3) ^ (row & 7)) << 3) + (k & 7);
}

// Stage 32 rows (this wave's slice) of a row-major [nrows x 64] fp32 matrix
// into LDS as bf16, swizzled. Coalesced float4 loads; barrier-free (each wave
// touches only rows [wb, wb+32)).
__device__ __forceinline__ void stage_rows_bf16(
    const float* __restrict__ srcmat, long row0, int wb, int lane,
    __bf16* sT, long nrows)
{
#pragma unroll
    for (int i = 0; i < 8; ++i) {
        const int f = (i * 64 + lane) * 4;   // flat over 32*64 floats
        const int rl = f >> 6;
        const int k  = f & 63;
        const int r_loc = wb + rl;
        const long r = row0 + r_loc;
        float4 v = {0.f, 0.f, 0.f, 0.f};
        if (r < nrows) v = *(const float4*)&srcmat[(size_t)r * 64 + k];
        bf16x4 pk = { (__bf16)v.x, (__bf16)v.y, (__bf16)v.z, (__bf16)v.w };
        *(bf16x4*)&sT[swz(r_loc, k)] = pk;
    }
}

// A-frag for mfma_f32_16x16x32_bf16: lane holds A[m=lane&15][k=quad*8+j]
__device__ __forceinline__ bf16x8 afrag(const __bf16* sT, int row, int ks, int q) {
    return *(const bf16x8*)&sT[swz(row, ks * 32 + q * 8)];
}

// ---------------------------------------------------------------------------
// prep: convert the 5 weight matrices to bf16 in B-frag order in ws.
// Frag slot s = (ks*NT + nt)*64 + lane holds B[k=ks*32+(lane>>4)*8+j][n=nt*16+(lane&15)]
// ---------------------------------------------------------------------------
__device__ __forceinline__ void conv_frag(const float* __restrict__ W, int N,
                                          __bf16* __restrict__ dst, int tid) {
    const int NT = N / 16;
    const int slots = 2 * NT * 64;
    for (int s = tid; s < slots; s += 256) {
        const int ks = s / (NT * 64);
        const int nt = (s / 64) % NT;
        const int lane = s % 64;
        const int q = lane >> 4, lc = lane & 15;
#pragma unroll
        for (int j = 0; j < 8; ++j) {
            const int k = ks * 32 + q * 8 + j;
            dst[(size_t)s * 8 + j] = (__bf16)W[(size_t)k * N + nt * 16 + lc];
        }
    }
}

__global__ __launch_bounds__(256) void prep_kernel(
    const float* __restrict__ Wv, const float* __restrict__ Wr,
    const float* __restrict__ We, const float* __restrict__ W1,
    const float* __restrict__ W2,
    __bf16* wfv, __bf16* wfr, __bf16* wfe, __bf16* wf1, __bf16* wf2)
{
    const int t = threadIdx.x;
    conv_frag(Wv, 64, wfv, t);
    conv_frag(Wr, 64, wfr, t);
    conv_frag(We, 64, wfe, t);
    conv_frag(W1, 64, wf1, t);
    conv_frag(W2, 32, wf2, t);
}

// ---------------------------------------------------------------------------
// node: vskb = bf16(feat@Wv + bv), vrkb = bf16(feat@Wr + br). 128 nodes/block.
// ---------------------------------------------------------------------------
__global__ __launch_bounds__(256, 4) void node_kernel(
    const float* __restrict__ feat,
    const float* __restrict__ bv, const float* __restrict__ br,
    const __bf16* __restrict__ wfv, const __bf16* __restrict__ wfr,
    __bf16* __restrict__ vskb, __bf16* __restrict__ vrkb)
{
    __shared__ __align__(16) __bf16 sT[128 * 64];
    const int tid = threadIdx.x;
    const int lane = tid & 63, w = tid >> 6;
    const int q = lane >> 4, lc = lane & 15;
    const long n0 = (long)blockIdx.x * 128;
    const int wb = w * 32;

    stage_rows_bf16(feat, n0, wb, lane, sT, (long)N_NODES);

    bf16x8 a[2][2];
#pragma unroll
    for (int mt = 0; mt < 2; ++mt)
#pragma unroll
        for (int ks = 0; ks < 2; ++ks)
            a[mt][ks] = afrag(sT, wb + mt * 16 + lc, ks, q);

    const __bf16* wf[2] = {wfv, wfr};
    const float* bias[2] = {bv, br};
    __bf16* dstp[2] = {vskb, vrkb};

    for (int m = 0; m < 2; ++m) {
        bf16x8 bfr[4][2];
#pragma unroll
        for (int nt = 0; nt < 4; ++nt)
#pragma unroll
            for (int ks = 0; ks < 2; ++ks)
                bfr[nt][ks] = *(const bf16x8*)&wf[m][((size_t)(ks * 4 + nt) * 64 + lane) * 8];

        f32x4 acc[2][4];
#pragma unroll
        for (int mt = 0; mt < 2; ++mt)
#pragma unroll
            for (int nt = 0; nt < 4; ++nt) {
                f32x4 z = {0.f, 0.f, 0.f, 0.f};
                acc[mt][nt] = z;
            }
#pragma unroll
        for (int ks = 0; ks < 2; ++ks)
#pragma unroll
            for (int mt = 0; mt < 2; ++mt)
#pragma unroll
                for (int nt = 0; nt < 4; ++nt)
                    acc[mt][nt] = MFMA16(a[mt][ks], bfr[nt][ks], acc[mt][nt]);

        float bb[4];
#pragma unroll
        for (int nt = 0; nt < 4; ++nt) bb[nt] = bias[m][nt * 16 + lc];

#pragma unroll
        for (int mt = 0; mt < 2; ++mt)
#pragma unroll
            for (int r = 0; r < 4; ++r) {
                const long node = n0 + wb + mt * 16 + q * 4 + r;
                if (node < N_NODES) {
#pragma unroll
                    for (int nt = 0; nt < 4; ++nt)
                        dstp[m][(size_t)node * 64 + nt * 16 + lc] =
                            (__bf16)(acc[mt][nt][r] + bb[nt]);
                }
            }
    }
}

// ---------------------------------------------------------------------------
// edge: h = relu(ek + vsk[src] + vrk[dst] + bek); h1 = relu(h@W1+b1);
//       out = relu(h1@W2+b2). 128 edges/block, barrier-free (wave-private rows),
//       single 16KB LDS buffer reused efeat -> h -> h1.
// ---------------------------------------------------------------------------
__global__ __launch_bounds__(256, 4) void edge_kernel(
    const float* __restrict__ efeat,
    const int* __restrict__ src, const int* __restrict__ dst,
    const __bf16* __restrict__ vskb, const __bf16* __restrict__ vrkb,
    const __bf16* __restrict__ wfe, const __bf16* __restrict__ wf1,
    const __bf16* __restrict__ wf2,
    const float* __restrict__ bek, const float* __restrict__ b1,
    const float* __restrict__ b2,
    float* __restrict__ out)
{
    __shared__ __align__(16) __bf16 sT[128 * 64];
    const int tid = threadIdx.x;
    const int lane = tid & 63, w = tid >> 6;
    const int q = lane >> 4, lc = lane & 15;
    const long e0 = (long)blockIdx.x * 128;
    const int wb = w * 32;

    // ---- stage efeat (own 32 rows) + pull A-frags ----
    stage_rows_bf16(efeat, e0, wb, lane, sT, (long)N_EDGES);

    bf16x8 a[2][2];
#pragma unroll
    for (int mt = 0; mt < 2; ++mt)
#pragma unroll
        for (int ks = 0; ks < 2; ++ks)
            a[mt][ks] = afrag(sT, wb + mt * 16 + lc, ks, q);

    // ---- GEMM1: ek = efeat @ Wek ----
    {
        bf16x8 bfr[4][2];
#pragma unroll
        for (int nt = 0; nt < 4; ++nt)
#pragma unroll
            for (int ks = 0; ks < 2; ++ks)
                bfr[nt][ks] = *(const bf16x8*)&wfe[((size_t)(ks * 4 + nt) * 64 + lane) * 8];

        f32x4 acc[2][4];
#pragma unroll
        for (int mt = 0; mt < 2; ++mt)
#pragma unroll
            for (int nt = 0; nt < 4; ++nt) {
                f32x4 z = {0.f, 0.f, 0.f, 0.f};
                acc[mt][nt] = z;
            }
#pragma unroll
        for (int ks = 0; ks < 2; ++ks)
#pragma unroll
            for (int mt = 0; mt < 2; ++mt)
#pragma unroll
                for (int nt = 0; nt < 4; ++nt)
                    acc[mt][nt] = MFMA16(a[mt][ks], bfr[nt][ks], acc[mt][nt]);

        float bb[4];
#pragma unroll
        for (int nt = 0; nt < 4; ++nt) bb[nt] = bek[nt * 16 + lc];

        // ---- epilogue 1: gather + add + relu -> h (bf16, back into sT) ----
#pragma unroll
        for (int mt = 0; mt < 2; ++mt)
#pragma unroll
            for (int r = 0; r < 4; ++r) {
                const int e_loc = wb + mt * 16 + q * 4 + r;
                const long e = e0 + e_loc;
                const bool valid = e < N_EDGES;
                int si = 0, di = 0;
                if (valid) { si = src[e]; di = dst[e]; }
#pragma unroll
                for (int nt = 0; nt < 4; ++nt) {
                    const int col = nt * 16 + lc;
                    float hv = 0.f;
                    if (valid) {
                        const float gs = (float)vskb[(size_t)si * 64 + col];
                        const float gd = (float)vrkb[(size_t)di * 64 + col];
                        hv = fmaxf(acc[mt][nt][r] + gs + gd + bb[nt], 0.f);
                    }
                    sT[swz(e_loc, col)] = (__bf16)hv;
                }
            }
    }

    // ---- GEMM2: h1 = relu(h @ W1 + b1) ----
    {
#pragma unroll
        for (int mt = 0; mt < 2; ++mt)
#pragma unroll
            for (int ks = 0; ks < 2; ++ks)
                a[mt][ks] = afrag(sT, wb + mt * 16 + lc, ks, q);

        bf16x8 bfr[4][2];
#pragma unroll
        for (int nt = 0; nt < 4; ++nt)
#pragma unroll
            for (int ks = 0; ks < 2; ++ks)
                bfr[nt][ks] = *(const bf16x8*)&wf1[((size_t)(ks * 4 + nt) * 64 + lane) * 8];

        f32x4 acc[2][4];
#pragma unroll
        for (int mt = 0; mt < 2; ++mt)
#pragma unroll
            for (int nt = 0; nt < 4; ++nt) {
                f32x4 z = {0.f, 0.f, 0.f, 0.f};
                acc[mt][nt] = z;
            }
#pragma unroll
        for (int ks = 0; ks < 2; ++ks)
#pragma unroll
            for (int mt = 0; mt < 2; ++mt)
#pragma unroll
                for (int nt = 0; nt < 4; ++nt)
                    acc[mt][nt] = MFMA16(a[mt][ks], bfr[nt][ks], acc[mt][nt]);

        float bb[4];
#pragma unroll
        for (int nt = 0; nt < 4; ++nt) bb[nt] = b1[nt * 16 + lc];

#pragma unroll
        for (int mt = 0; mt < 2; ++mt)
#pragma unroll
            for (int r = 0; r < 4; ++r) {
                const int e_loc = wb + mt * 16 + q * 4 + r;
#pragma unroll
                for (int nt = 0; nt < 4; ++nt) {
                    const int col = nt * 16 + lc;
                    const float hv = fmaxf(acc[mt][nt][r] + bb[nt], 0.f);
                    sT[swz(e_loc, col)] = (__bf16)hv;
                }
            }
    }

    // ---- GEMM3: out = relu(h1 @ W2 + b2) ----
    {
#pragma unroll
        for (int mt = 0; mt < 2; ++mt)
#pragma unroll
            for (int ks = 0; ks < 2; ++ks)
                a[mt][ks] = afrag(sT, wb + mt * 16 + lc, ks, q);

        bf16x8 bfr[2][2];
#pragma unroll
        for (int nt = 0; nt < 2; ++nt)
#pragma unroll
            for (int ks = 0; ks < 2; ++ks)
                bfr[nt][ks] = *(const bf16x8*)&wf2[((size_t)(ks * 2 + nt) * 64 + lane) * 8];

        f32x4 acc[2][2];
#pragma unroll
        for (int mt = 0; mt < 2; ++mt)
#pragma unroll
            for (int nt = 0; nt < 2; ++nt) {
                f32x4 z = {0.f, 0.f, 0.f, 0.f};
                acc[mt][nt] = z;
            }
#pragma unroll
        for (int ks = 0; ks < 2; ++ks)
#pragma unroll
            for (int mt = 0; mt < 2; ++mt)
#pragma unroll
                for (int nt = 0; nt < 2; ++nt)
                    acc[mt][nt] = MFMA16(a[mt][ks], bfr[nt][ks], acc[mt][nt]);

        float bb[2] = {b2[lc], b2[16 + lc]};

#pragma unroll
        for (int mt = 0; mt < 2; ++mt)
#pragma unroll
            for (int r = 0; r < 4; ++r) {
                const long e = e0 + wb + mt * 16 + q * 4 + r;
                if (e < N_EDGES) {
#pragma unroll
                    for (int nt = 0; nt < 2; ++nt)
                        out[(size_t)e * 32 + nt * 16 + lc] =
                            fmaxf(acc[mt][nt][r] + bb[nt], 0.f);
                }
            }
    }
}

extern "C" void kernel_launch(void* const* d_in, const int* in_sizes, int n_in,
                              void* d_out, int out_size, void* d_ws, size_t ws_size,
                              hipStream_t stream) {
    const float* feat  = (const float*)d_in[0];
    const float* efeat = (const float*)d_in[1];
    const int*   src   = (const int*)d_in[2];
    const int*   dst   = (const int*)d_in[3];
    const float* W_vsk = (const float*)d_in[4];
    const float* b_vsk = (const float*)d_in[5];
    const float* W_vrk = (const float*)d_in[6];
    const float* b_vrk = (const float*)d_in[7];
    const float* W_ek  = (const float*)d_in[8];
    const float* b_ek  = (const float*)d_in[9];
    const float* W1    = (const float*)d_in[10];
    const float* b1    = (const float*)d_in[11];
    const float* W2    = (const float*)d_in[12];
    const float* b2    = (const float*)d_in[13];
    float* out = (float*)d_out;

    // ws: vskb(12.8MB) | vrkb(12.8MB) | 5 weight frag blocks (36KB)
    __bf16* vskb = (__bf16*)d_ws;
    __bf16* vrkb = vskb + (size_t)N_NODES * 64;
    __bf16* wfv  = vrkb + (size_t)N_NODES * 64;
    __bf16* wfr  = wfv + 4096;
    __bf16* wfe  = wfr + 4096;
    __bf16* wf1  = wfe + 4096;
    __bf16* wf2  = wf1 + 4096;   // 2048 elems

    prep_kernel<<<1, 256, 0, stream>>>(W_vsk, W_vrk, W_ek, W1, W2,
                                       wfv, wfr, wfe, wf1, wf2);

    const int node_blocks = (N_NODES + 127) / 128;   // 782
    node_kernel<<<node_blocks, 256, 0, stream>>>(feat, b_vsk, b_vrk,
                                                 wfv, wfr, vskb, vrkb);

    const int edge_blocks = (N_EDGES + 127) / 128;   // 9766
    edge_kernel<<<edge_blocks, 256, 0, stream>>>(efeat, src, dst, vskb, vrkb,
                                                 wfe, wf1, wf2,
                                                 b_ek, b1, b2, out);
}